// Round 8
// baseline (233.640 us; speedup 1.0000x reference)
//
#include <hip/hip_runtime.h>
#include <hip/hip_bf16.h>

// DirGCNConv on MI355X - round 8.
// out = 0.5*(A@x)@W_src + 0.5*(A^T@x)@W_dst + 0.5*(b_src+b_dst)
//   k_prep     : XCD-sliced ushort bins; edge reads NON-TEMPORAL so the 51 MB
//                edge stream doesn't evict partially-filled bin lines from L2
//                (round-7 counters: WRITE 63 MB = ~6x bin-line re-writeback).
//   k_aux      : fused dinv (sc = deg^-1/2) + W pack (fp32 -> bf16 B-fragments)
//   k_gemm_mfma: hF = 0.5*sc_col*x@W_src, hB = 0.5*sc_row*x@W_dst via
//                v_mfma_f32_16x16x32_bf16, A-frags from global, bf16 h out.
//   k_gather   : one wave per node, both directions + bias fused, register acc.

constexpr int N_NODES = 50000;
constexpr int N_EDGES = 800000;
constexpr int D = 128;
constexpr int D2 = D / 2;
constexpr int CAP = 48;    // max bin capacity; deg ~ Poisson(16), P(>48) ~ 2e-6
constexpr int NSLICE = 8;  // = XCDs
constexpr int NPS = (N_NODES + NSLICE - 1) / NSLICE;   // 6250 nodes per slice
constexpr int CHUNK = 2048;
constexpr int NCHUNK = (N_EDGES + CHUNK - 1) / CHUNK;  // 391

typedef __bf16 bf16x8 __attribute__((ext_vector_type(8)));
typedef float  f32x4  __attribute__((ext_vector_type(4)));

// ---------- XCD-sliced bin build + degree counting (nt edge loads) ----------
__global__ __launch_bounds__(256) void k_prep(const int* __restrict__ row,
                                              const int* __restrict__ col,
                                              int* __restrict__ cntF,
                                              int* __restrict__ cntB,
                                              unsigned short* __restrict__ binF,
                                              unsigned short* __restrict__ binB) {
    const int slice = blockIdx.x & 7;          // round-robin blockIdx -> XCD heuristic
    const int chunk = blockIdx.x >> 3;
    const int lo = slice * NPS;
    const int hi = min(lo + NPS, N_NODES);
    const int e1 = min((chunk + 1) * CHUNK, N_EDGES);
    for (int e = chunk * CHUNK + threadIdx.x; e < e1; e += 256) {
        int r = __builtin_nontemporal_load(&row[e]);
        int c = __builtin_nontemporal_load(&col[e]);
        if (r >= lo && r < hi) {
            int p = atomicAdd(&cntF[r], 1);
            if (p < CAP) binF[(size_t)r * CAP + p] = (unsigned short)c;
        }
        if (c >= lo && c < hi) {
            int p = atomicAdd(&cntB[c], 1);
            if (p < CAP) binB[(size_t)c * CAP + p] = (unsigned short)r;
        }
    }
}

// ---------- fused: dinv (blocks 0..195) + W pack (blocks 196..211) ----------
// packW: frag f = (dir*8 + ct)*4 + ks; lane holds
//   B[k = ks*32 + (lane>>4)*8 + j][n = ct*16 + (lane&15)], j = 0..7.
__global__ __launch_bounds__(256) void k_aux(const int* __restrict__ cntF,
                                             const int* __restrict__ cntB,
                                             float* __restrict__ sc_row,
                                             float* __restrict__ sc_col,
                                             const float* __restrict__ Wsrc,
                                             const float* __restrict__ Wdst,
                                             __hip_bfloat16* __restrict__ Wpk) {
    const int NB_DINV = (N_NODES + 255) / 256;     // 196
    if (blockIdx.x < NB_DINV) {
        int i = blockIdx.x * 256 + threadIdx.x;
        if (i < N_NODES) {
            int a = cntF[i];
            sc_row[i] = (a > 0) ? rsqrtf((float)a) : 0.f;
            int b = cntB[i];
            sc_col[i] = (b > 0) ? rsqrtf((float)b) : 0.f;
        }
        return;
    }
    int tid = (blockIdx.x - NB_DINV) * 256 + threadIdx.x;   // 0..4095
    int f = tid >> 6;
    int lane = tid & 63;
    int dir = f >> 5;
    int ct = (f >> 2) & 7;
    int ks = f & 3;
    const float* W = dir ? Wdst : Wsrc;
    int k0 = ks * 32 + (lane >> 4) * 8;
    int n = ct * 16 + (lane & 15);
    __hip_bfloat16 v[8];
    #pragma unroll
    for (int j = 0; j < 8; ++j) v[j] = __float2bfloat16(W[(k0 + j) * D + n]);
    *(bf16x8*)&Wpk[(size_t)tid * 8] = *(const bf16x8*)v;
}

// ---------- MFMA GEMM: both directions, 64 nodes/block ----------
__global__ __launch_bounds__(256) void k_gemm_mfma(const float* __restrict__ x,
                                                   const bf16x8* __restrict__ Wpk,
                                                   const float* __restrict__ sc_col,
                                                   const float* __restrict__ sc_row,
                                                   __hip_bfloat16* __restrict__ hF,
                                                   __hip_bfloat16* __restrict__ hB) {
    const int wave = threadIdx.x >> 6;
    const int lane = threadIdx.x & 63;
    const int quad = lane >> 4;
    const int m0 = blockIdx.x * 64 + wave * 16;

    // A fragments: lane holds A[m = lane&15][k = ks*32 + quad*8 + j]
    const int arow = min(m0 + (lane & 15), N_NODES - 1);
    bf16x8 a[4];
    #pragma unroll
    for (int ks = 0; ks < 4; ++ks) {
        const float* px = &x[(size_t)arow * D + ks * 32 + quad * 8];
        float4 v0 = *(const float4*)px;
        float4 v1 = *(const float4*)(px + 4);
        union { bf16x8 v; __hip_bfloat16 e[8]; } u;
        u.e[0] = __float2bfloat16(v0.x); u.e[1] = __float2bfloat16(v0.y);
        u.e[2] = __float2bfloat16(v0.z); u.e[3] = __float2bfloat16(v0.w);
        u.e[4] = __float2bfloat16(v1.x); u.e[5] = __float2bfloat16(v1.y);
        u.e[6] = __float2bfloat16(v1.z); u.e[7] = __float2bfloat16(v1.w);
        a[ks] = u.v;
    }

    // per-lane row scales for the 4 C rows (row = quad*4 + reg)
    const int crow = m0 + quad * 4;
    float fF[4], fB[4];
    #pragma unroll
    for (int r = 0; r < 4; ++r) {
        int nd = min(crow + r, N_NODES - 1);
        fF[r] = 0.5f * sc_col[nd];
        fB[r] = 0.5f * sc_row[nd];
    }

    const bf16x8* WpkF = Wpk;             // dir 0: frags 0..31
    const bf16x8* WpkB = Wpk + 32 * 64;   // dir 1: frags 32..63

    #pragma unroll
    for (int ct = 0; ct < 8; ++ct) {
        f32x4 cF = {0.f, 0.f, 0.f, 0.f};
        f32x4 cB = {0.f, 0.f, 0.f, 0.f};
        #pragma unroll
        for (int ks = 0; ks < 4; ++ks) {
            bf16x8 bF = WpkF[(ct * 4 + ks) * 64 + lane];
            bf16x8 bB = WpkB[(ct * 4 + ks) * 64 + lane];
            cF = __builtin_amdgcn_mfma_f32_16x16x32_bf16(a[ks], bF, cF, 0, 0, 0);
            cB = __builtin_amdgcn_mfma_f32_16x16x32_bf16(a[ks], bB, cB, 0, 0, 0);
        }
        const int colb = ct * 16 + (lane & 15);
        #pragma unroll
        for (int r = 0; r < 4; ++r) {
            int nd = crow + r;
            if (nd < N_NODES) {
                hF[(size_t)nd * D + colb] = __float2bfloat16(fF[r] * cF[r]);
                hB[(size_t)nd * D + colb] = __float2bfloat16(fB[r] * cB[r]);
            }
        }
    }
}

// ---------- fused gather: out = bias + sc_row*sum hF[srcF] + sc_col*sum hB[srcB] ----------
__global__ __launch_bounds__(256) void k_gather(const unsigned short* __restrict__ binF,
                                                const int* __restrict__ cntF,
                                                const unsigned short* __restrict__ binB,
                                                const int* __restrict__ cntB,
                                                const float* __restrict__ sc_row,
                                                const float* __restrict__ sc_col,
                                                const __hip_bfloat162* __restrict__ hF,
                                                const __hip_bfloat162* __restrict__ hB,
                                                const float* __restrict__ b_src,
                                                const float* __restrict__ b_dst,
                                                float* __restrict__ out) {
    const int node = blockIdx.x * 4 + (threadIdx.x >> 6);
    const int lane = threadIdx.x & 63;
    const int nF = min(cntF[node], CAP);
    const int nB = min(cntB[node], CAP);

    int entF = (lane < nF) ? (int)binF[(size_t)node * CAP + lane] : 0;
    int entB = (lane < nB) ? (int)binB[(size_t)node * CAP + lane] : 0;

    float2 accF = make_float2(0.f, 0.f);
    {
        int i = 0;
        for (; i + 3 < nF; i += 4) {
            int s0 = __shfl(entF, i), s1 = __shfl(entF, i + 1);
            int s2 = __shfl(entF, i + 2), s3 = __shfl(entF, i + 3);
            float2 h0 = __bfloat1622float2(hF[(size_t)s0 * D2 + lane]);
            float2 h1 = __bfloat1622float2(hF[(size_t)s1 * D2 + lane]);
            float2 h2 = __bfloat1622float2(hF[(size_t)s2 * D2 + lane]);
            float2 h3 = __bfloat1622float2(hF[(size_t)s3 * D2 + lane]);
            accF.x += h0.x + h1.x + h2.x + h3.x;
            accF.y += h0.y + h1.y + h2.y + h3.y;
        }
        for (; i < nF; ++i) {
            int s = __shfl(entF, i);
            float2 hv = __bfloat1622float2(hF[(size_t)s * D2 + lane]);
            accF.x += hv.x;
            accF.y += hv.y;
        }
    }
    float2 accB = make_float2(0.f, 0.f);
    {
        int i = 0;
        for (; i + 3 < nB; i += 4) {
            int s0 = __shfl(entB, i), s1 = __shfl(entB, i + 1);
            int s2 = __shfl(entB, i + 2), s3 = __shfl(entB, i + 3);
            float2 h0 = __bfloat1622float2(hB[(size_t)s0 * D2 + lane]);
            float2 h1 = __bfloat1622float2(hB[(size_t)s1 * D2 + lane]);
            float2 h2 = __bfloat1622float2(hB[(size_t)s2 * D2 + lane]);
            float2 h3 = __bfloat1622float2(hB[(size_t)s3 * D2 + lane]);
            accB.x += h0.x + h1.x + h2.x + h3.x;
            accB.y += h0.y + h1.y + h2.y + h3.y;
        }
        for (; i < nB; ++i) {
            int s = __shfl(entB, i);
            float2 hv = __bfloat1622float2(hB[(size_t)s * D2 + lane]);
            accB.x += hv.x;
            accB.y += hv.y;
        }
    }

    float2 bs = *(const float2*)&b_src[lane * 2];
    float2 bd = *(const float2*)&b_dst[lane * 2];
    float sF = sc_row[node];
    float sB = sc_col[node];
    float2 o;
    o.x = 0.5f * (bs.x + bd.x) + sF * accF.x + sB * accB.x;
    o.y = 0.5f * (bs.y + bd.y) + sF * accF.y + sB * accB.y;
    *(float2*)&out[(size_t)node * D + lane * 2] = o;
}

extern "C" void kernel_launch(void* const* d_in, const int* in_sizes, int n_in,
                              void* d_out, int out_size, void* d_ws, size_t ws_size,
                              hipStream_t stream) {
    const float* x     = (const float*)d_in[0];
    const int*   edges = (const int*)d_in[1];      // [2, E]: row then col
    const float* W_src = (const float*)d_in[2];
    const float* b_src = (const float*)d_in[3];
    const float* W_dst = (const float*)d_in[4];
    const float* b_dst = (const float*)d_in[5];
    float* out = (float*)d_out;

    const int* row = edges;
    const int* col = edges + N_EDGES;

    // ---- workspace layout (~36 MB) ----
    __hip_bfloat16* hFu    = (__hip_bfloat16*)d_ws;                 // 6.4M bf16 (12.8 MB)
    __hip_bfloat16* hBu    = hFu + (size_t)N_NODES * D;             // 12.8 MB
    __hip_bfloat16* Wpk    = hBu + (size_t)N_NODES * D;             // 64 frags*512 bf16 = 64 KB
    float*          sc_row = (float*)(Wpk + 64 * 512);              // 50k floats
    float*          sc_col = sc_row + N_NODES;                      // 50k floats
    int*            cntF   = (int*)(sc_col + N_NODES);              // 50k ints (zeroed)
    int*            cntB   = cntF + N_NODES;                        // 50k ints (zeroed)
    unsigned short* binF   = (unsigned short*)(cntB + N_NODES);     // 50k*CAP ushorts
    unsigned short* binB   = binF + (size_t)N_NODES * CAP;          // 50k*CAP ushorts

    (void)hipMemsetAsync(cntF, 0, 2 * (size_t)N_NODES * sizeof(int), stream);

    const int gP = NCHUNK * NSLICE;            // 3128
    const int gN = (N_NODES + 255) / 256;      // 196
    const int gA = gN + 16;                    // dinv + packW fused
    const int gM = (N_NODES + 63) / 64;        // 782
    const int gG = N_NODES / 4;                // 12500 (exact)

    k_prep<<<gP, 256, 0, stream>>>(row, col, cntF, cntB, binF, binB);
    k_aux<<<gA, 256, 0, stream>>>(cntF, cntB, sc_row, sc_col, W_src, W_dst, Wpk);
    k_gemm_mfma<<<gM, 256, 0, stream>>>(x, (const bf16x8*)Wpk, sc_col, sc_row, hFu, hBu);
    k_gather<<<gG, 256, 0, stream>>>(binF, cntF, binB, cntB, sc_row, sc_col,
                                     (const __hip_bfloat162*)hFu,
                                     (const __hip_bfloat162*)hBu,
                                     b_src, b_dst, out);
}

// Round 9
// 203.686 us; speedup vs baseline: 1.1471x; 1.1471x over previous
//
#include <hip/hip_runtime.h>
#include <hip/hip_bf16.h>

// DirGCNConv on MI355X - round 9.
// out = 0.5*(A@x)@W_src + 0.5*(A^T@x)@W_dst + 0.5*(b_src+b_dst)
//   k_part     : partition edges into 98 dst-buckets (512 nodes each) per dir;
//                LDS count -> one global-atomic reservation per bucket per
//                block -> contiguous 4B entry runs (writeback ~= payload).
//   k_bin      : per bucket, build 512-node ushort bins in LDS (ds_add
//                counters = true degrees), coalesced uint4 copy-out.
//   k_aux      : fused dinv (sc = deg^-1/2) + W pack (fp32 -> bf16 B-frags)
//   k_gemm_mfma: hF = 0.5*sc_col*x@W_src, hB = 0.5*sc_row*x@W_dst via
//                v_mfma_f32_16x16x32_bf16, A-frags from global, bf16 h out.
//   k_gather   : one wave per node, both directions + bias fused, register acc.

constexpr int N_NODES = 50000;
constexpr int N_EDGES = 800000;
constexpr int D = 128;
constexpr int D2 = D / 2;
constexpr int CAP = 48;     // bin capacity per node; deg ~ Poisson(16), P(>48) ~ 2e-6
constexpr int NPBK = 512;   // nodes per bucket
constexpr int NBUK = (N_NODES + NPBK - 1) / NPBK;      // 98 buckets
constexpr int ECH = 8192;   // edges per k_part chunk
constexpr int NCH = (N_EDGES + ECH - 1) / ECH;         // 98 chunks
constexpr int CAPB = 12288; // bucket entry capacity (mean 8163, sigma ~90)

typedef __bf16 bf16x8 __attribute__((ext_vector_type(8)));
typedef float  f32x4  __attribute__((ext_vector_type(4)));

// ---------- phase 1: partition edges by dst bucket, contiguous runs ----------
__global__ __launch_bounds__(256) void k_part(const int* __restrict__ row,
                                              const int* __restrict__ col,
                                              int* __restrict__ tail,       // [2*NBUK] zeroed
                                              unsigned* __restrict__ part) {
    __shared__ int cnt[NBUK], base[NBUK], pos[NBUK];
    const int dir = blockIdx.x & 1;
    const int chunk = blockIdx.x >> 1;
    const int* dst = dir ? col : row;
    const int* src = dir ? row : col;
    for (int i = threadIdx.x; i < NBUK; i += 256) { cnt[i] = 0; pos[i] = 0; }
    __syncthreads();
    const int e0 = chunk * ECH;
    const int e1 = min(e0 + ECH, N_EDGES);
    for (int e = e0 + threadIdx.x; e < e1; e += 256)
        atomicAdd(&cnt[dst[e] >> 9], 1);
    __syncthreads();
    for (int i = threadIdx.x; i < NBUK; i += 256)
        base[i] = (cnt[i] > 0) ? atomicAdd(&tail[dir * NBUK + i], cnt[i]) : 0;
    __syncthreads();
    for (int e = e0 + threadIdx.x; e < e1; e += 256) {
        int d = dst[e], s = src[e];
        int b = d >> 9;
        int p = base[b] + atomicAdd(&pos[b], 1);
        if (p < CAPB)
            part[((size_t)dir * NBUK + b) * CAPB + p] =
                ((unsigned)(d & (NPBK - 1)) << 16) | (unsigned)s;
    }
}

// ---------- phase 2: per-bucket LDS binning + coalesced copy-out ----------
__global__ __launch_bounds__(256) void k_bin(const int* __restrict__ tail,
                                             const unsigned* __restrict__ part,
                                             unsigned short* __restrict__ binF,
                                             unsigned short* __restrict__ binB,
                                             int* __restrict__ cntF,
                                             int* __restrict__ cntB) {
    __shared__ alignas(16) unsigned short bins[NPBK * CAP];  // 49152 B
    __shared__ int cnt[NPBK];                                // 2048 B
    const int dir = blockIdx.x & 1;
    const int b = blockIdx.x >> 1;
    for (int i = threadIdx.x; i < NPBK; i += 256) cnt[i] = 0;
    __syncthreads();
    const int n = min(tail[dir * NBUK + b], CAPB);
    const unsigned* p = &part[((size_t)dir * NBUK + b) * CAPB];
    for (int i = threadIdx.x; i < n; i += 256) {
        unsigned ent = p[i];
        int dl = ent >> 16;
        int q = atomicAdd(&cnt[dl], 1);
        if (q < CAP) bins[dl * CAP + q] = (unsigned short)(ent & 0xFFFFu);
    }
    __syncthreads();
    unsigned short* gbin = dir ? binB : binF;
    int* gcnt = dir ? cntB : cntF;
    const int node0 = b * NPBK;
    const int nv = min(NPBK, N_NODES - node0);       // valid nodes this bucket
    // copy bins: nv*CAP ushorts = nv*6 uint4 (CAP*2B = 96 B = 6 x 16B per node)
    const int nq = nv * (CAP * 2 / 16);
    const uint4* bw = (const uint4*)bins;
    uint4* gw = (uint4*)&gbin[(size_t)node0 * CAP];
    for (int i = threadIdx.x; i < nq; i += 256) gw[i] = bw[i];
    for (int i = threadIdx.x; i < nv; i += 256) gcnt[node0 + i] = cnt[i];
}

// ---------- fused: dinv (blocks 0..195) + W pack (blocks 196..211) ----------
__global__ __launch_bounds__(256) void k_aux(const int* __restrict__ cntF,
                                             const int* __restrict__ cntB,
                                             float* __restrict__ sc_row,
                                             float* __restrict__ sc_col,
                                             const float* __restrict__ Wsrc,
                                             const float* __restrict__ Wdst,
                                             __hip_bfloat16* __restrict__ Wpk) {
    const int NB_DINV = (N_NODES + 255) / 256;     // 196
    if (blockIdx.x < NB_DINV) {
        int i = blockIdx.x * 256 + threadIdx.x;
        if (i < N_NODES) {
            int a = cntF[i];
            sc_row[i] = (a > 0) ? rsqrtf((float)a) : 0.f;
            int b = cntB[i];
            sc_col[i] = (b > 0) ? rsqrtf((float)b) : 0.f;
        }
        return;
    }
    int tid = (blockIdx.x - NB_DINV) * 256 + threadIdx.x;   // 0..4095
    int f = tid >> 6;
    int lane = tid & 63;
    int dir = f >> 5;
    int ct = (f >> 2) & 7;
    int ks = f & 3;
    const float* W = dir ? Wdst : Wsrc;
    int k0 = ks * 32 + (lane >> 4) * 8;
    int n = ct * 16 + (lane & 15);
    __hip_bfloat16 v[8];
    #pragma unroll
    for (int j = 0; j < 8; ++j) v[j] = __float2bfloat16(W[(k0 + j) * D + n]);
    *(bf16x8*)&Wpk[(size_t)tid * 8] = *(const bf16x8*)v;
}

// ---------- MFMA GEMM: both directions, 64 nodes/block ----------
__global__ __launch_bounds__(256) void k_gemm_mfma(const float* __restrict__ x,
                                                   const bf16x8* __restrict__ Wpk,
                                                   const float* __restrict__ sc_col,
                                                   const float* __restrict__ sc_row,
                                                   __hip_bfloat16* __restrict__ hF,
                                                   __hip_bfloat16* __restrict__ hB) {
    const int wave = threadIdx.x >> 6;
    const int lane = threadIdx.x & 63;
    const int quad = lane >> 4;
    const int m0 = blockIdx.x * 64 + wave * 16;

    const int arow = min(m0 + (lane & 15), N_NODES - 1);
    bf16x8 a[4];
    #pragma unroll
    for (int ks = 0; ks < 4; ++ks) {
        const float* px = &x[(size_t)arow * D + ks * 32 + quad * 8];
        float4 v0 = *(const float4*)px;
        float4 v1 = *(const float4*)(px + 4);
        union { bf16x8 v; __hip_bfloat16 e[8]; } u;
        u.e[0] = __float2bfloat16(v0.x); u.e[1] = __float2bfloat16(v0.y);
        u.e[2] = __float2bfloat16(v0.z); u.e[3] = __float2bfloat16(v0.w);
        u.e[4] = __float2bfloat16(v1.x); u.e[5] = __float2bfloat16(v1.y);
        u.e[6] = __float2bfloat16(v1.z); u.e[7] = __float2bfloat16(v1.w);
        a[ks] = u.v;
    }

    const int crow = m0 + quad * 4;
    float fF[4], fB[4];
    #pragma unroll
    for (int r = 0; r < 4; ++r) {
        int nd = min(crow + r, N_NODES - 1);
        fF[r] = 0.5f * sc_col[nd];
        fB[r] = 0.5f * sc_row[nd];
    }

    const bf16x8* WpkF = Wpk;             // dir 0: frags 0..31
    const bf16x8* WpkB = Wpk + 32 * 64;   // dir 1: frags 32..63

    #pragma unroll
    for (int ct = 0; ct < 8; ++ct) {
        f32x4 cF = {0.f, 0.f, 0.f, 0.f};
        f32x4 cB = {0.f, 0.f, 0.f, 0.f};
        #pragma unroll
        for (int ks = 0; ks < 4; ++ks) {
            bf16x8 bF = WpkF[(ct * 4 + ks) * 64 + lane];
            bf16x8 bB = WpkB[(ct * 4 + ks) * 64 + lane];
            cF = __builtin_amdgcn_mfma_f32_16x16x32_bf16(a[ks], bF, cF, 0, 0, 0);
            cB = __builtin_amdgcn_mfma_f32_16x16x32_bf16(a[ks], bB, cB, 0, 0, 0);
        }
        const int colb = ct * 16 + (lane & 15);
        #pragma unroll
        for (int r = 0; r < 4; ++r) {
            int nd = crow + r;
            if (nd < N_NODES) {
                hF[(size_t)nd * D + colb] = __float2bfloat16(fF[r] * cF[r]);
                hB[(size_t)nd * D + colb] = __float2bfloat16(fB[r] * cB[r]);
            }
        }
    }
}

// ---------- fused gather: out = bias + sc_row*sum hF[srcF] + sc_col*sum hB[srcB] ----------
__global__ __launch_bounds__(256) void k_gather(const unsigned short* __restrict__ binF,
                                                const int* __restrict__ cntF,
                                                const unsigned short* __restrict__ binB,
                                                const int* __restrict__ cntB,
                                                const float* __restrict__ sc_row,
                                                const float* __restrict__ sc_col,
                                                const __hip_bfloat162* __restrict__ hF,
                                                const __hip_bfloat162* __restrict__ hB,
                                                const float* __restrict__ b_src,
                                                const float* __restrict__ b_dst,
                                                float* __restrict__ out) {
    const int node = blockIdx.x * 4 + (threadIdx.x >> 6);
    const int lane = threadIdx.x & 63;
    const int nF = min(cntF[node], CAP);
    const int nB = min(cntB[node], CAP);

    int entF = (lane < nF) ? (int)binF[(size_t)node * CAP + lane] : 0;
    int entB = (lane < nB) ? (int)binB[(size_t)node * CAP + lane] : 0;

    float2 accF = make_float2(0.f, 0.f);
    {
        int i = 0;
        for (; i + 3 < nF; i += 4) {
            int s0 = __shfl(entF, i), s1 = __shfl(entF, i + 1);
            int s2 = __shfl(entF, i + 2), s3 = __shfl(entF, i + 3);
            float2 h0 = __bfloat1622float2(hF[(size_t)s0 * D2 + lane]);
            float2 h1 = __bfloat1622float2(hF[(size_t)s1 * D2 + lane]);
            float2 h2 = __bfloat1622float2(hF[(size_t)s2 * D2 + lane]);
            float2 h3 = __bfloat1622float2(hF[(size_t)s3 * D2 + lane]);
            accF.x += h0.x + h1.x + h2.x + h3.x;
            accF.y += h0.y + h1.y + h2.y + h3.y;
        }
        for (; i < nF; ++i) {
            int s = __shfl(entF, i);
            float2 hv = __bfloat1622float2(hF[(size_t)s * D2 + lane]);
            accF.x += hv.x;
            accF.y += hv.y;
        }
    }
    float2 accB = make_float2(0.f, 0.f);
    {
        int i = 0;
        for (; i + 3 < nB; i += 4) {
            int s0 = __shfl(entB, i), s1 = __shfl(entB, i + 1);
            int s2 = __shfl(entB, i + 2), s3 = __shfl(entB, i + 3);
            float2 h0 = __bfloat1622float2(hB[(size_t)s0 * D2 + lane]);
            float2 h1 = __bfloat1622float2(hB[(size_t)s1 * D2 + lane]);
            float2 h2 = __bfloat1622float2(hB[(size_t)s2 * D2 + lane]);
            float2 h3 = __bfloat1622float2(hB[(size_t)s3 * D2 + lane]);
            accB.x += h0.x + h1.x + h2.x + h3.x;
            accB.y += h0.y + h1.y + h2.y + h3.y;
        }
        for (; i < nB; ++i) {
            int s = __shfl(entB, i);
            float2 hv = __bfloat1622float2(hB[(size_t)s * D2 + lane]);
            accB.x += hv.x;
            accB.y += hv.y;
        }
    }

    float2 bs = *(const float2*)&b_src[lane * 2];
    float2 bd = *(const float2*)&b_dst[lane * 2];
    float sF = sc_row[node];
    float sB = sc_col[node];
    float2 o;
    o.x = 0.5f * (bs.x + bd.x) + sF * accF.x + sB * accB.x;
    o.y = 0.5f * (bs.y + bd.y) + sF * accF.y + sB * accB.y;
    *(float2*)&out[(size_t)node * D + lane * 2] = o;
}

extern "C" void kernel_launch(void* const* d_in, const int* in_sizes, int n_in,
                              void* d_out, int out_size, void* d_ws, size_t ws_size,
                              hipStream_t stream) {
    const float* x     = (const float*)d_in[0];
    const int*   edges = (const int*)d_in[1];      // [2, E]: row then col
    const float* W_src = (const float*)d_in[2];
    const float* b_src = (const float*)d_in[3];
    const float* W_dst = (const float*)d_in[4];
    const float* b_dst = (const float*)d_in[5];
    float* out = (float*)d_out;

    const int* row = edges;
    const int* col = edges + N_EDGES;

    // ---- workspace layout (~45.7 MB; >=60.4 MB proven available in r4) ----
    __hip_bfloat16* hFu    = (__hip_bfloat16*)d_ws;                 // 12.8 MB
    __hip_bfloat16* hBu    = hFu + (size_t)N_NODES * D;             // 12.8 MB
    __hip_bfloat16* Wpk    = hBu + (size_t)N_NODES * D;             // 64 KB
    float*          sc_row = (float*)(Wpk + 64 * 512);              // 200 KB
    float*          sc_col = sc_row + N_NODES;                      // 200 KB
    int*            cntF   = (int*)(sc_col + N_NODES);              // 200 KB
    int*            cntB   = cntF + N_NODES;                        // 200 KB
    int*            tail   = cntB + N_NODES;                        // 256 ints (zeroed)
    unsigned*       part   = (unsigned*)(tail + 256);               // 9.63 MB
    unsigned short* binF   = (unsigned short*)(part + (size_t)2 * NBUK * CAPB); // 4.8 MB
    unsigned short* binB   = binF + (size_t)N_NODES * CAP;          // 4.8 MB

    (void)hipMemsetAsync(tail, 0, 256 * sizeof(int), stream);

    const int gP = NCH * 2;                    // 196
    const int gB = NBUK * 2;                   // 196
    const int gN = (N_NODES + 255) / 256;      // 196
    const int gA = gN + 16;                    // dinv + packW fused
    const int gM = (N_NODES + 63) / 64;        // 782
    const int gG = N_NODES / 4;                // 12500 (exact)

    k_part<<<gP, 256, 0, stream>>>(row, col, tail, part);
    k_bin<<<gB, 256, 0, stream>>>(tail, part, binF, binB, cntF, cntB);
    k_aux<<<gA, 256, 0, stream>>>(cntF, cntB, sc_row, sc_col, W_src, W_dst, Wpk);
    k_gemm_mfma<<<gM, 256, 0, stream>>>(x, (const bf16x8*)Wpk, sc_col, sc_row, hFu, hBu);
    k_gather<<<gG, 256, 0, stream>>>(binF, cntF, binB, cntB, sc_row, sc_col,
                                     (const __hip_bfloat162*)hFu,
                                     (const __hip_bfloat162*)hBu,
                                     b_src, b_dst, out);
}

// Round 11
// 199.850 us; speedup vs baseline: 1.1691x; 1.0192x over previous
//
#include <hip/hip_runtime.h>
#include <hip/hip_bf16.h>

// DirGCNConv on MI355X - round 11 (r10 + divergent-shfl fix).
// out = 0.5*(A@x)@W_src + 0.5*(A^T@x)@W_dst + 0.5*(b_src+b_dst)
//   k_part     : partition edges into 98 dst-buckets (512 nodes each) per dir.
//   k_bin      : per bucket, build 512-node ushort bins in LDS, coalesced copy-out.
//   k_aux      : fused dinv (sc = deg^-1/2) + W pack (fp32 -> bf16 B-frags)
//   k_gemm_mfma: hF = 0.5*sc_col*x@W_src, hB = 0.5*sc_row*x@W_dst (MFMA bf16).
//   k_gather   : one wave per node; half-wave split, 8 B loads, 8 rows in
//                flight. NOTE: all __shfl ops hoisted to converged control
//                flow — ds_bpermute from a lane inactive under divergence
//                returns 0 (r10 bug: odd-degree tail read lane >= 32 from a
//                lower-half-only branch -> added h[0] instead of real row).

constexpr int N_NODES = 50000;
constexpr int N_EDGES = 800000;
constexpr int D = 128;
constexpr int CAP = 48;     // bin capacity per node; dataset max degree < 48
constexpr int NPBK = 512;   // nodes per bucket
constexpr int NBUK = (N_NODES + NPBK - 1) / NPBK;      // 98 buckets
constexpr int ECH = 8192;   // edges per k_part chunk
constexpr int NCH = (N_EDGES + ECH - 1) / ECH;         // 98 chunks
constexpr int CAPB = 12288; // bucket entry capacity (mean 8163, sigma ~90)

typedef __bf16 bf16x8 __attribute__((ext_vector_type(8)));
typedef float  f32x4  __attribute__((ext_vector_type(4)));

// ---------- phase 1: partition edges by dst bucket, contiguous runs ----------
__global__ __launch_bounds__(256) void k_part(const int* __restrict__ row,
                                              const int* __restrict__ col,
                                              int* __restrict__ tail,       // [2*NBUK] zeroed
                                              unsigned* __restrict__ part) {
    __shared__ int cnt[NBUK], base[NBUK], pos[NBUK];
    const int dir = blockIdx.x & 1;
    const int chunk = blockIdx.x >> 1;
    const int* dst = dir ? col : row;
    const int* src = dir ? row : col;
    for (int i = threadIdx.x; i < NBUK; i += 256) { cnt[i] = 0; pos[i] = 0; }
    __syncthreads();
    const int e0 = chunk * ECH;
    const int e1 = min(e0 + ECH, N_EDGES);
    for (int e = e0 + threadIdx.x; e < e1; e += 256)
        atomicAdd(&cnt[dst[e] >> 9], 1);
    __syncthreads();
    for (int i = threadIdx.x; i < NBUK; i += 256)
        base[i] = (cnt[i] > 0) ? atomicAdd(&tail[dir * NBUK + i], cnt[i]) : 0;
    __syncthreads();
    for (int e = e0 + threadIdx.x; e < e1; e += 256) {
        int d = dst[e], s = src[e];
        int b = d >> 9;
        int p = base[b] + atomicAdd(&pos[b], 1);
        if (p < CAPB)
            part[((size_t)dir * NBUK + b) * CAPB + p] =
                ((unsigned)(d & (NPBK - 1)) << 16) | (unsigned)s;
    }
}

// ---------- phase 2: per-bucket LDS binning + coalesced copy-out ----------
__global__ __launch_bounds__(256) void k_bin(const int* __restrict__ tail,
                                             const unsigned* __restrict__ part,
                                             unsigned short* __restrict__ binF,
                                             unsigned short* __restrict__ binB,
                                             int* __restrict__ cntF,
                                             int* __restrict__ cntB) {
    __shared__ alignas(16) unsigned short bins[NPBK * CAP];  // 49152 B
    __shared__ int cnt[NPBK];                                // 2048 B
    const int dir = blockIdx.x & 1;
    const int b = blockIdx.x >> 1;
    for (int i = threadIdx.x; i < NPBK; i += 256) cnt[i] = 0;
    __syncthreads();
    const int n = min(tail[dir * NBUK + b], CAPB);
    const unsigned* p = &part[((size_t)dir * NBUK + b) * CAPB];
    for (int i = threadIdx.x; i < n; i += 256) {
        unsigned ent = p[i];
        int dl = ent >> 16;
        int q = atomicAdd(&cnt[dl], 1);
        if (q < CAP) bins[dl * CAP + q] = (unsigned short)(ent & 0xFFFFu);
    }
    __syncthreads();
    unsigned short* gbin = dir ? binB : binF;
    int* gcnt = dir ? cntB : cntF;
    const int node0 = b * NPBK;
    const int nv = min(NPBK, N_NODES - node0);
    const int nq = nv * (CAP * 2 / 16);      // 16 B chunks
    const uint4* bw = (const uint4*)bins;
    uint4* gw = (uint4*)&gbin[(size_t)node0 * CAP];
    for (int i = threadIdx.x; i < nq; i += 256) gw[i] = bw[i];
    for (int i = threadIdx.x; i < nv; i += 256) gcnt[node0 + i] = cnt[i];
}

// ---------- fused: dinv (blocks 0..195) + W pack (blocks 196..211) ----------
__global__ __launch_bounds__(256) void k_aux(const int* __restrict__ cntF,
                                             const int* __restrict__ cntB,
                                             float* __restrict__ sc_row,
                                             float* __restrict__ sc_col,
                                             const float* __restrict__ Wsrc,
                                             const float* __restrict__ Wdst,
                                             __hip_bfloat16* __restrict__ Wpk) {
    const int NB_DINV = (N_NODES + 255) / 256;     // 196
    if (blockIdx.x < NB_DINV) {
        int i = blockIdx.x * 256 + threadIdx.x;
        if (i < N_NODES) {
            int a = cntF[i];
            sc_row[i] = (a > 0) ? rsqrtf((float)a) : 0.f;
            int b = cntB[i];
            sc_col[i] = (b > 0) ? rsqrtf((float)b) : 0.f;
        }
        return;
    }
    int tid = (blockIdx.x - NB_DINV) * 256 + threadIdx.x;   // 0..4095
    int f = tid >> 6;
    int lane = tid & 63;
    int dir = f >> 5;
    int ct = (f >> 2) & 7;
    int ks = f & 3;
    const float* W = dir ? Wdst : Wsrc;
    int k0 = ks * 32 + (lane >> 4) * 8;
    int n = ct * 16 + (lane & 15);
    __hip_bfloat16 v[8];
    #pragma unroll
    for (int j = 0; j < 8; ++j) v[j] = __float2bfloat16(W[(k0 + j) * D + n]);
    *(bf16x8*)&Wpk[(size_t)tid * 8] = *(const bf16x8*)v;
}

// ---------- MFMA GEMM: both directions, 64 nodes/block ----------
__global__ __launch_bounds__(256) void k_gemm_mfma(const float* __restrict__ x,
                                                   const bf16x8* __restrict__ Wpk,
                                                   const float* __restrict__ sc_col,
                                                   const float* __restrict__ sc_row,
                                                   __hip_bfloat16* __restrict__ hF,
                                                   __hip_bfloat16* __restrict__ hB) {
    const int wave = threadIdx.x >> 6;
    const int lane = threadIdx.x & 63;
    const int quad = lane >> 4;
    const int m0 = blockIdx.x * 64 + wave * 16;

    const int arow = min(m0 + (lane & 15), N_NODES - 1);
    bf16x8 a[4];
    #pragma unroll
    for (int ks = 0; ks < 4; ++ks) {
        const float* px = &x[(size_t)arow * D + ks * 32 + quad * 8];
        float4 v0 = *(const float4*)px;
        float4 v1 = *(const float4*)(px + 4);
        union { bf16x8 v; __hip_bfloat16 e[8]; } u;
        u.e[0] = __float2bfloat16(v0.x); u.e[1] = __float2bfloat16(v0.y);
        u.e[2] = __float2bfloat16(v0.z); u.e[3] = __float2bfloat16(v0.w);
        u.e[4] = __float2bfloat16(v1.x); u.e[5] = __float2bfloat16(v1.y);
        u.e[6] = __float2bfloat16(v1.z); u.e[7] = __float2bfloat16(v1.w);
        a[ks] = u.v;
    }

    const int crow = m0 + quad * 4;
    float fF[4], fB[4];
    #pragma unroll
    for (int r = 0; r < 4; ++r) {
        int nd = min(crow + r, N_NODES - 1);
        fF[r] = 0.5f * sc_col[nd];
        fB[r] = 0.5f * sc_row[nd];
    }

    const bf16x8* WpkF = Wpk;             // dir 0: frags 0..31
    const bf16x8* WpkB = Wpk + 32 * 64;   // dir 1: frags 32..63

    #pragma unroll
    for (int ct = 0; ct < 8; ++ct) {
        f32x4 cF = {0.f, 0.f, 0.f, 0.f};
        f32x4 cB = {0.f, 0.f, 0.f, 0.f};
        #pragma unroll
        for (int ks = 0; ks < 4; ++ks) {
            bf16x8 bF = WpkF[(ct * 4 + ks) * 64 + lane];
            bf16x8 bB = WpkB[(ct * 4 + ks) * 64 + lane];
            cF = __builtin_amdgcn_mfma_f32_16x16x32_bf16(a[ks], bF, cF, 0, 0, 0);
            cB = __builtin_amdgcn_mfma_f32_16x16x32_bf16(a[ks], bB, cB, 0, 0, 0);
        }
        const int colb = ct * 16 + (lane & 15);
        #pragma unroll
        for (int r = 0; r < 4; ++r) {
            int nd = crow + r;
            if (nd < N_NODES) {
                hF[(size_t)nd * D + colb] = __float2bfloat16(fF[r] * cF[r]);
                hB[(size_t)nd * D + colb] = __float2bfloat16(fB[r] * cB[r]);
            }
        }
    }
}

// bf16x4 (as uint2) -> float4, shift/mask unpack (4 VALU ops)
__device__ __forceinline__ float4 bf4_to_f4(uint2 u) {
    union { unsigned i; float f; } a, b, c, d;
    a.i = u.x << 16;
    b.i = u.x & 0xFFFF0000u;
    c.i = u.y << 16;
    d.i = u.y & 0xFFFF0000u;
    return make_float4(a.f, b.f, c.f, d.f);
}

// ---------- fused gather: half-wave 2-rows-per-load, 8 rows in flight ----------
// lane = half*32 + l32; half h accumulates edges {h, h+2, h+4, ...};
// lane covers dims [l32*4 .. l32*4+3]. All __shfl in converged flow.
__global__ __launch_bounds__(256) void k_gather(const unsigned short* __restrict__ binF,
                                                const int* __restrict__ cntF,
                                                const unsigned short* __restrict__ binB,
                                                const int* __restrict__ cntB,
                                                const float* __restrict__ sc_row,
                                                const float* __restrict__ sc_col,
                                                const uint2* __restrict__ hF,   // row = 32 uint2
                                                const uint2* __restrict__ hB,
                                                const float* __restrict__ b_src,
                                                const float* __restrict__ b_dst,
                                                float* __restrict__ out) {
    const int node = blockIdx.x * 4 + (threadIdx.x >> 6);
    const int lane = threadIdx.x & 63;
    const int half = lane >> 5;
    const int l32 = lane & 31;
    const int nF = min(cntF[node], CAP);
    const int nB = min(cntB[node], CAP);

    // coalesced preload of entry lists: one ushort per lane
    int entF = (lane < nF) ? (int)binF[(size_t)node * CAP + lane] : 0;
    int entB = (lane < nB) ? (int)binB[(size_t)node * CAP + lane] : 0;

    // tail sources hoisted to CONVERGED control flow (r10 bug: shfl under
    // divergence pulls 0 from lanes inactive in the branch)
    const int sTailF = __shfl(entF, (nF > 0) ? nF - 1 : 0);
    const int sTailB = __shfl(entB, (nB > 0) ? nB - 1 : 0);

    float4 accF = make_float4(0.f, 0.f, 0.f, 0.f);
    {
        const int npair = nF >> 1;
        int i = 0;
        for (; i + 3 < npair; i += 4) {
            int s0 = __shfl(entF, 2 * i + half);
            int s1 = __shfl(entF, 2 * (i + 1) + half);
            int s2 = __shfl(entF, 2 * (i + 2) + half);
            int s3 = __shfl(entF, 2 * (i + 3) + half);
            uint2 v0 = hF[(size_t)s0 * 32 + l32];
            uint2 v1 = hF[(size_t)s1 * 32 + l32];
            uint2 v2 = hF[(size_t)s2 * 32 + l32];
            uint2 v3 = hF[(size_t)s3 * 32 + l32];
            float4 f0 = bf4_to_f4(v0), f1 = bf4_to_f4(v1);
            float4 f2 = bf4_to_f4(v2), f3 = bf4_to_f4(v3);
            accF.x += (f0.x + f1.x) + (f2.x + f3.x);
            accF.y += (f0.y + f1.y) + (f2.y + f3.y);
            accF.z += (f0.z + f1.z) + (f2.z + f3.z);
            accF.w += (f0.w + f1.w) + (f2.w + f3.w);
        }
        for (; i < npair; ++i) {
            int s = __shfl(entF, 2 * i + half);
            float4 f = bf4_to_f4(hF[(size_t)s * 32 + l32]);
            accF.x += f.x; accF.y += f.y; accF.z += f.z; accF.w += f.w;
        }
        if ((nF & 1) && half == 0) {           // odd tail: lower half only
            float4 f = bf4_to_f4(hF[(size_t)sTailF * 32 + l32]);
            accF.x += f.x; accF.y += f.y; accF.z += f.z; accF.w += f.w;
        }
    }
    float4 accB = make_float4(0.f, 0.f, 0.f, 0.f);
    {
        const int npair = nB >> 1;
        int i = 0;
        for (; i + 3 < npair; i += 4) {
            int s0 = __shfl(entB, 2 * i + half);
            int s1 = __shfl(entB, 2 * (i + 1) + half);
            int s2 = __shfl(entB, 2 * (i + 2) + half);
            int s3 = __shfl(entB, 2 * (i + 3) + half);
            uint2 v0 = hB[(size_t)s0 * 32 + l32];
            uint2 v1 = hB[(size_t)s1 * 32 + l32];
            uint2 v2 = hB[(size_t)s2 * 32 + l32];
            uint2 v3 = hB[(size_t)s3 * 32 + l32];
            float4 f0 = bf4_to_f4(v0), f1 = bf4_to_f4(v1);
            float4 f2 = bf4_to_f4(v2), f3 = bf4_to_f4(v3);
            accB.x += (f0.x + f1.x) + (f2.x + f3.x);
            accB.y += (f0.y + f1.y) + (f2.y + f3.y);
            accB.z += (f0.z + f1.z) + (f2.z + f3.z);
            accB.w += (f0.w + f1.w) + (f2.w + f3.w);
        }
        for (; i < npair; ++i) {
            int s = __shfl(entB, 2 * i + half);
            float4 f = bf4_to_f4(hB[(size_t)s * 32 + l32]);
            accB.x += f.x; accB.y += f.y; accB.z += f.z; accB.w += f.w;
        }
        if ((nB & 1) && half == 0) {
            float4 f = bf4_to_f4(hB[(size_t)sTailB * 32 + l32]);
            accB.x += f.x; accB.y += f.y; accB.z += f.z; accB.w += f.w;
        }
    }

    // combine halves (each dim lives in both halves at the same l32)
    accF.x += __shfl_xor(accF.x, 32);
    accF.y += __shfl_xor(accF.y, 32);
    accF.z += __shfl_xor(accF.z, 32);
    accF.w += __shfl_xor(accF.w, 32);
    accB.x += __shfl_xor(accB.x, 32);
    accB.y += __shfl_xor(accB.y, 32);
    accB.z += __shfl_xor(accB.z, 32);
    accB.w += __shfl_xor(accB.w, 32);

    if (half == 0) {
        float4 bs = *(const float4*)&b_src[l32 * 4];
        float4 bd = *(const float4*)&b_dst[l32 * 4];
        float sF = sc_row[node];
        float sB = sc_col[node];
        float4 o;
        o.x = 0.5f * (bs.x + bd.x) + sF * accF.x + sB * accB.x;
        o.y = 0.5f * (bs.y + bd.y) + sF * accF.y + sB * accB.y;
        o.z = 0.5f * (bs.z + bd.z) + sF * accF.z + sB * accB.z;
        o.w = 0.5f * (bs.w + bd.w) + sF * accF.w + sB * accB.w;
        *(float4*)&out[(size_t)node * D + l32 * 4] = o;
    }
}

extern "C" void kernel_launch(void* const* d_in, const int* in_sizes, int n_in,
                              void* d_out, int out_size, void* d_ws, size_t ws_size,
                              hipStream_t stream) {
    const float* x     = (const float*)d_in[0];
    const int*   edges = (const int*)d_in[1];      // [2, E]: row then col
    const float* W_src = (const float*)d_in[2];
    const float* b_src = (const float*)d_in[3];
    const float* W_dst = (const float*)d_in[4];
    const float* b_dst = (const float*)d_in[5];
    float* out = (float*)d_out;

    const int* row = edges;
    const int* col = edges + N_EDGES;

    // ---- workspace layout (~45.7 MB) ----
    __hip_bfloat16* hFu    = (__hip_bfloat16*)d_ws;                 // 12.8 MB
    __hip_bfloat16* hBu    = hFu + (size_t)N_NODES * D;             // 12.8 MB
    __hip_bfloat16* Wpk    = hBu + (size_t)N_NODES * D;             // 64 KB
    float*          sc_row = (float*)(Wpk + 64 * 512);              // 200 KB
    float*          sc_col = sc_row + N_NODES;                      // 200 KB
    int*            cntF   = (int*)(sc_col + N_NODES);              // 200 KB
    int*            cntB   = cntF + N_NODES;                        // 200 KB
    int*            tail   = cntB + N_NODES;                        // 256 ints (zeroed)
    unsigned*       part   = (unsigned*)(tail + 256);               // 9.63 MB
    unsigned short* binF   = (unsigned short*)(part + (size_t)2 * NBUK * CAPB); // 4.8 MB
    unsigned short* binB   = binF + (size_t)N_NODES * CAP;          // 4.8 MB

    (void)hipMemsetAsync(tail, 0, 256 * sizeof(int), stream);

    const int gP = NCH * 2;                    // 196
    const int gB = NBUK * 2;                   // 196
    const int gN = (N_NODES + 255) / 256;      // 196
    const int gA = gN + 16;                    // dinv + packW fused
    const int gM = (N_NODES + 63) / 64;        // 782
    const int gG = N_NODES / 4;                // 12500 (exact)

    k_part<<<gP, 256, 0, stream>>>(row, col, tail, part);
    k_bin<<<gB, 256, 0, stream>>>(tail, part, binF, binB, cntF, cntB);
    k_aux<<<gA, 256, 0, stream>>>(cntF, cntB, sc_row, sc_col, W_src, W_dst, Wpk);
    k_gemm_mfma<<<gM, 256, 0, stream>>>(x, (const bf16x8*)Wpk, sc_col, sc_row, hFu, hBu);
    k_gather<<<gG, 256, 0, stream>>>(binF, cntF, binB, cntB, sc_row, sc_col,
                                     (const uint2*)hFu, (const uint2*)hBu,
                                     b_src, b_dst, out);
}

// Round 12
// 197.112 us; speedup vs baseline: 1.1853x; 1.0139x over previous
//
#include <hip/hip_runtime.h>
#include <hip/hip_bf16.h>

// DirGCNConv on MI355X - round 12.
// out = 0.5*(A@x)@W_src + 0.5*(A^T@x)@W_dst + 0.5*(b_src+b_dst)
//   k_part     : partition edges into 98 dst-buckets per dir (ECH=2048 -> 782
//                blocks, 4x r11 parallelism) + 16 fused packW blocks.
//   k_bin      : per bucket, LDS ushort bins + fused dinv epilogue
//                (dir0 -> sc_row, dir1 -> sc_col). k_aux eliminated.
//   k_gemm_mfma: hF/hB via v_mfma_f32_16x16x32_bf16; Wpk (64 KB) staged in
//                LDS once per block (r11: every wave pulled 64 KB via L1/L2).
//   k_gather   : UNCHANGED from r11 — FETCH=179 MB is the combinatorial
//                minimum (43k distinct rows x 256 B x 8 XCD x 2 dir); it runs
//                at the L2 line-fill ceiling (~2.4 lines/cyc/XCD). Reference
//                dispatch for attribution.

constexpr int N_NODES = 50000;
constexpr int N_EDGES = 800000;
constexpr int D = 128;
constexpr int CAP = 48;     // bin capacity per node; dataset max degree < 48
constexpr int NPBK = 512;   // nodes per bucket
constexpr int NBUK = (N_NODES + NPBK - 1) / NPBK;      // 98 buckets
constexpr int ECH = 2048;   // edges per k_part chunk
constexpr int NCH = (N_EDGES + ECH - 1) / ECH;         // 391
constexpr int CAPB = 12288; // bucket entry capacity (mean 8163, sigma ~90)

typedef __bf16 bf16x8 __attribute__((ext_vector_type(8)));
typedef float  f32x4  __attribute__((ext_vector_type(4)));

// ---------- phase 1: partition edges by dst bucket (+16 packW blocks) ----------
__global__ __launch_bounds__(256) void k_part(const int* __restrict__ row,
                                              const int* __restrict__ col,
                                              int* __restrict__ tail,       // [2*NBUK] zeroed
                                              unsigned* __restrict__ part,
                                              const float* __restrict__ Wsrc,
                                              const float* __restrict__ Wdst,
                                              __hip_bfloat16* __restrict__ Wpk) {
    const int bid = blockIdx.x;
    if (bid >= NCH * 2) {
        // ---- packW: frag f = (dir*8+ct)*4+ks; lane holds
        //      B[k = ks*32+(lane>>4)*8+j][n = ct*16+(lane&15)], j=0..7
        int tid = (bid - NCH * 2) * 256 + threadIdx.x;   // 0..4095
        int f = tid >> 6;
        int lane = tid & 63;
        int dir = f >> 5;
        int ct = (f >> 2) & 7;
        int ks = f & 3;
        const float* W = dir ? Wdst : Wsrc;
        int k0 = ks * 32 + (lane >> 4) * 8;
        int n = ct * 16 + (lane & 15);
        __hip_bfloat16 v[8];
        #pragma unroll
        for (int j = 0; j < 8; ++j) v[j] = __float2bfloat16(W[(k0 + j) * D + n]);
        *(bf16x8*)&Wpk[(size_t)tid * 8] = *(const bf16x8*)v;
        return;
    }
    __shared__ int cnt[NBUK], base[NBUK], pos[NBUK];
    const int dir = bid & 1;
    const int chunk = bid >> 1;
    const int* dst = dir ? col : row;
    const int* src = dir ? row : col;
    for (int i = threadIdx.x; i < NBUK; i += 256) { cnt[i] = 0; pos[i] = 0; }
    __syncthreads();
    const int e0 = chunk * ECH;
    const int e1 = min(e0 + ECH, N_EDGES);
    for (int e = e0 + threadIdx.x; e < e1; e += 256)
        atomicAdd(&cnt[dst[e] >> 9], 1);
    __syncthreads();
    for (int i = threadIdx.x; i < NBUK; i += 256)
        base[i] = (cnt[i] > 0) ? atomicAdd(&tail[dir * NBUK + i], cnt[i]) : 0;
    __syncthreads();
    for (int e = e0 + threadIdx.x; e < e1; e += 256) {
        int d = dst[e], s = src[e];
        int b = d >> 9;
        int p = base[b] + atomicAdd(&pos[b], 1);
        if (p < CAPB)
            part[((size_t)dir * NBUK + b) * CAPB + p] =
                ((unsigned)(d & (NPBK - 1)) << 16) | (unsigned)s;
    }
}

// ---------- phase 2: per-bucket LDS binning + fused dinv epilogue ----------
__global__ __launch_bounds__(256) void k_bin(const int* __restrict__ tail,
                                             const unsigned* __restrict__ part,
                                             unsigned short* __restrict__ binF,
                                             unsigned short* __restrict__ binB,
                                             int* __restrict__ cntF,
                                             int* __restrict__ cntB,
                                             float* __restrict__ sc_row,
                                             float* __restrict__ sc_col) {
    __shared__ alignas(16) unsigned short bins[NPBK * CAP];  // 49152 B
    __shared__ int cnt[NPBK];                                // 2048 B
    const int dir = blockIdx.x & 1;
    const int b = blockIdx.x >> 1;
    for (int i = threadIdx.x; i < NPBK; i += 256) cnt[i] = 0;
    __syncthreads();
    const int n = min(tail[dir * NBUK + b], CAPB);
    const unsigned* p = &part[((size_t)dir * NBUK + b) * CAPB];
    for (int i = threadIdx.x; i < n; i += 256) {
        unsigned ent = p[i];
        int dl = ent >> 16;
        int q = atomicAdd(&cnt[dl], 1);
        if (q < CAP) bins[dl * CAP + q] = (unsigned short)(ent & 0xFFFFu);
    }
    __syncthreads();
    unsigned short* gbin = dir ? binB : binF;
    int* gcnt = dir ? cntB : cntF;
    float* sc = dir ? sc_col : sc_row;     // dir0: dst=row -> out-deg -> sc_row
    const int node0 = b * NPBK;
    const int nv = min(NPBK, N_NODES - node0);
    const int nq = nv * (CAP * 2 / 16);    // 16 B chunks
    const uint4* bw = (const uint4*)bins;
    uint4* gw = (uint4*)&gbin[(size_t)node0 * CAP];
    for (int i = threadIdx.x; i < nq; i += 256) gw[i] = bw[i];
    for (int i = threadIdx.x; i < nv; i += 256) {
        int c = cnt[i];
        gcnt[node0 + i] = c;
        sc[node0 + i] = (c > 0) ? rsqrtf((float)c) : 0.f;
    }
}

// ---------- MFMA GEMM: both directions, 64 nodes/block, Wpk in LDS ----------
__global__ __launch_bounds__(256) void k_gemm_mfma(const float* __restrict__ x,
                                                   const bf16x8* __restrict__ Wpk,
                                                   const float* __restrict__ sc_col,
                                                   const float* __restrict__ sc_row,
                                                   __hip_bfloat16* __restrict__ hF,
                                                   __hip_bfloat16* __restrict__ hB) {
    __shared__ bf16x8 Bs[64 * 64];     // all 64 B-frags, 64 KB
    for (int i = threadIdx.x; i < 64 * 64; i += 256) Bs[i] = Wpk[i];

    const int wave = threadIdx.x >> 6;
    const int lane = threadIdx.x & 63;
    const int quad = lane >> 4;
    const int m0 = blockIdx.x * 64 + wave * 16;

    // A fragments: lane holds A[m = lane&15][k = ks*32 + quad*8 + j]
    const int arow = min(m0 + (lane & 15), N_NODES - 1);
    bf16x8 a[4];
    #pragma unroll
    for (int ks = 0; ks < 4; ++ks) {
        const float* px = &x[(size_t)arow * D + ks * 32 + quad * 8];
        float4 v0 = *(const float4*)px;
        float4 v1 = *(const float4*)(px + 4);
        union { bf16x8 v; __hip_bfloat16 e[8]; } u;
        u.e[0] = __float2bfloat16(v0.x); u.e[1] = __float2bfloat16(v0.y);
        u.e[2] = __float2bfloat16(v0.z); u.e[3] = __float2bfloat16(v0.w);
        u.e[4] = __float2bfloat16(v1.x); u.e[5] = __float2bfloat16(v1.y);
        u.e[6] = __float2bfloat16(v1.z); u.e[7] = __float2bfloat16(v1.w);
        a[ks] = u.v;
    }

    const int crow = m0 + quad * 4;
    float fF[4], fB[4];
    #pragma unroll
    for (int r = 0; r < 4; ++r) {
        int nd = min(crow + r, N_NODES - 1);
        fF[r] = 0.5f * sc_col[nd];
        fB[r] = 0.5f * sc_row[nd];
    }

    __syncthreads();

    #pragma unroll
    for (int ct = 0; ct < 8; ++ct) {
        f32x4 cF = {0.f, 0.f, 0.f, 0.f};
        f32x4 cB = {0.f, 0.f, 0.f, 0.f};
        #pragma unroll
        for (int ks = 0; ks < 4; ++ks) {
            bf16x8 bF = Bs[(ct * 4 + ks) * 64 + lane];
            bf16x8 bB = Bs[(32 + ct * 4 + ks) * 64 + lane];
            cF = __builtin_amdgcn_mfma_f32_16x16x32_bf16(a[ks], bF, cF, 0, 0, 0);
            cB = __builtin_amdgcn_mfma_f32_16x16x32_bf16(a[ks], bB, cB, 0, 0, 0);
        }
        const int colb = ct * 16 + (lane & 15);
        #pragma unroll
        for (int r = 0; r < 4; ++r) {
            int nd = crow + r;
            if (nd < N_NODES) {
                hF[(size_t)nd * D + colb] = __float2bfloat16(fF[r] * cF[r]);
                hB[(size_t)nd * D + colb] = __float2bfloat16(fB[r] * cB[r]);
            }
        }
    }
}

// bf16x4 (as uint2) -> float4, shift/mask unpack (4 VALU ops)
__device__ __forceinline__ float4 bf4_to_f4(uint2 u) {
    union { unsigned i; float f; } a, b, c, d;
    a.i = u.x << 16;
    b.i = u.x & 0xFFFF0000u;
    c.i = u.y << 16;
    d.i = u.y & 0xFFFF0000u;
    return make_float4(a.f, b.f, c.f, d.f);
}

// ---------- fused gather (unchanged from r11) ----------
__global__ __launch_bounds__(256) void k_gather(const unsigned short* __restrict__ binF,
                                                const int* __restrict__ cntF,
                                                const unsigned short* __restrict__ binB,
                                                const int* __restrict__ cntB,
                                                const float* __restrict__ sc_row,
                                                const float* __restrict__ sc_col,
                                                const uint2* __restrict__ hF,   // row = 32 uint2
                                                const uint2* __restrict__ hB,
                                                const float* __restrict__ b_src,
                                                const float* __restrict__ b_dst,
                                                float* __restrict__ out) {
    const int node = blockIdx.x * 4 + (threadIdx.x >> 6);
    const int lane = threadIdx.x & 63;
    const int half = lane >> 5;
    const int l32 = lane & 31;
    const int nF = min(cntF[node], CAP);
    const int nB = min(cntB[node], CAP);

    int entF = (lane < nF) ? (int)binF[(size_t)node * CAP + lane] : 0;
    int entB = (lane < nB) ? (int)binB[(size_t)node * CAP + lane] : 0;

    // tail sources in CONVERGED flow (shfl under divergence pulls 0)
    const int sTailF = __shfl(entF, (nF > 0) ? nF - 1 : 0);
    const int sTailB = __shfl(entB, (nB > 0) ? nB - 1 : 0);

    float4 accF = make_float4(0.f, 0.f, 0.f, 0.f);
    {
        const int npair = nF >> 1;
        int i = 0;
        for (; i + 3 < npair; i += 4) {
            int s0 = __shfl(entF, 2 * i + half);
            int s1 = __shfl(entF, 2 * (i + 1) + half);
            int s2 = __shfl(entF, 2 * (i + 2) + half);
            int s3 = __shfl(entF, 2 * (i + 3) + half);
            uint2 v0 = hF[(size_t)s0 * 32 + l32];
            uint2 v1 = hF[(size_t)s1 * 32 + l32];
            uint2 v2 = hF[(size_t)s2 * 32 + l32];
            uint2 v3 = hF[(size_t)s3 * 32 + l32];
            float4 f0 = bf4_to_f4(v0), f1 = bf4_to_f4(v1);
            float4 f2 = bf4_to_f4(v2), f3 = bf4_to_f4(v3);
            accF.x += (f0.x + f1.x) + (f2.x + f3.x);
            accF.y += (f0.y + f1.y) + (f2.y + f3.y);
            accF.z += (f0.z + f1.z) + (f2.z + f3.z);
            accF.w += (f0.w + f1.w) + (f2.w + f3.w);
        }
        for (; i < npair; ++i) {
            int s = __shfl(entF, 2 * i + half);
            float4 f = bf4_to_f4(hF[(size_t)s * 32 + l32]);
            accF.x += f.x; accF.y += f.y; accF.z += f.z; accF.w += f.w;
        }
        if ((nF & 1) && half == 0) {
            float4 f = bf4_to_f4(hF[(size_t)sTailF * 32 + l32]);
            accF.x += f.x; accF.y += f.y; accF.z += f.z; accF.w += f.w;
        }
    }
    float4 accB = make_float4(0.f, 0.f, 0.f, 0.f);
    {
        const int npair = nB >> 1;
        int i = 0;
        for (; i + 3 < npair; i += 4) {
            int s0 = __shfl(entB, 2 * i + half);
            int s1 = __shfl(entB, 2 * (i + 1) + half);
            int s2 = __shfl(entB, 2 * (i + 2) + half);
            int s3 = __shfl(entB, 2 * (i + 3) + half);
            uint2 v0 = hB[(size_t)s0 * 32 + l32];
            uint2 v1 = hB[(size_t)s1 * 32 + l32];
            uint2 v2 = hB[(size_t)s2 * 32 + l32];
            uint2 v3 = hB[(size_t)s3 * 32 + l32];
            float4 f0 = bf4_to_f4(v0), f1 = bf4_to_f4(v1);
            float4 f2 = bf4_to_f4(v2), f3 = bf4_to_f4(v3);
            accB.x += (f0.x + f1.x) + (f2.x + f3.x);
            accB.y += (f0.y + f1.y) + (f2.y + f3.y);
            accB.z += (f0.z + f1.z) + (f2.z + f3.z);
            accB.w += (f0.w + f1.w) + (f2.w + f3.w);
        }
        for (; i < npair; ++i) {
            int s = __shfl(entB, 2 * i + half);
            float4 f = bf4_to_f4(hB[(size_t)s * 32 + l32]);
            accB.x += f.x; accB.y += f.y; accB.z += f.z; accB.w += f.w;
        }
        if ((nB & 1) && half == 0) {
            float4 f = bf4_to_f4(hB[(size_t)sTailB * 32 + l32]);
            accB.x += f.x; accB.y += f.y; accB.z += f.z; accB.w += f.w;
        }
    }

    accF.x += __shfl_xor(accF.x, 32);
    accF.y += __shfl_xor(accF.y, 32);
    accF.z += __shfl_xor(accF.z, 32);
    accF.w += __shfl_xor(accF.w, 32);
    accB.x += __shfl_xor(accB.x, 32);
    accB.y += __shfl_xor(accB.y, 32);
    accB.z += __shfl_xor(accB.z, 32);
    accB.w += __shfl_xor(accB.w, 32);

    if (half == 0) {
        float4 bs = *(const float4*)&b_src[l32 * 4];
        float4 bd = *(const float4*)&b_dst[l32 * 4];
        float sF = sc_row[node];
        float sB = sc_col[node];
        float4 o;
        o.x = 0.5f * (bs.x + bd.x) + sF * accF.x + sB * accB.x;
        o.y = 0.5f * (bs.y + bd.y) + sF * accF.y + sB * accB.y;
        o.z = 0.5f * (bs.z + bd.z) + sF * accF.z + sB * accB.z;
        o.w = 0.5f * (bs.w + bd.w) + sF * accF.w + sB * accB.w;
        *(float4*)&out[(size_t)node * D + l32 * 4] = o;
    }
}

extern "C" void kernel_launch(void* const* d_in, const int* in_sizes, int n_in,
                              void* d_out, int out_size, void* d_ws, size_t ws_size,
                              hipStream_t stream) {
    const float* x     = (const float*)d_in[0];
    const int*   edges = (const int*)d_in[1];      // [2, E]: row then col
    const float* W_src = (const float*)d_in[2];
    const float* b_src = (const float*)d_in[3];
    const float* W_dst = (const float*)d_in[4];
    const float* b_dst = (const float*)d_in[5];
    float* out = (float*)d_out;

    const int* row = edges;
    const int* col = edges + N_EDGES;

    // ---- workspace layout (~45.7 MB) ----
    __hip_bfloat16* hFu    = (__hip_bfloat16*)d_ws;                 // 12.8 MB
    __hip_bfloat16* hBu    = hFu + (size_t)N_NODES * D;             // 12.8 MB
    __hip_bfloat16* Wpk    = hBu + (size_t)N_NODES * D;             // 64 KB
    float*          sc_row = (float*)(Wpk + 64 * 512);              // 200 KB
    float*          sc_col = sc_row + N_NODES;                      // 200 KB
    int*            cntF   = (int*)(sc_col + N_NODES);              // 200 KB
    int*            cntB   = cntF + N_NODES;                        // 200 KB
    int*            tail   = cntB + N_NODES;                        // 256 ints (zeroed)
    unsigned*       part   = (unsigned*)(tail + 256);               // 9.63 MB
    unsigned short* binF   = (unsigned short*)(part + (size_t)2 * NBUK * CAPB); // 4.8 MB
    unsigned short* binB   = binF + (size_t)N_NODES * CAP;          // 4.8 MB

    (void)hipMemsetAsync(tail, 0, 256 * sizeof(int), stream);

    const int gP = NCH * 2 + 16;               // 798 (partition + packW)
    const int gB = NBUK * 2;                   // 196 (bin + dinv)
    const int gM = (N_NODES + 63) / 64;        // 782
    const int gG = N_NODES / 4;                // 12500 (exact)

    k_part<<<gP, 256, 0, stream>>>(row, col, tail, part, W_src, W_dst, Wpk);
    k_bin<<<gB, 256, 0, stream>>>(tail, part, binF, binB, cntF, cntB, sc_row, sc_col);
    k_gemm_mfma<<<gM, 256, 0, stream>>>(x, (const bf16x8*)Wpk, sc_col, sc_row, hFu, hBu);
    k_gather<<<gG, 256, 0, stream>>>(binF, cntF, binB, cntB, sc_row, sc_col,
                                     (const uint2*)hFu, (const uint2*)hBu,
                                     b_src, b_dst, out);
}